// Round 2
// baseline (398.658 us; speedup 1.0000x reference)
//
#include <hip/hip_runtime.h>
#include <hip/hip_bf16.h>
#include <math.h>

// Problem: B=4, C=64, H=W=128, O=64, K=3, pad=1, stride=1
// ws layout (floats): wt[9*64*64] | pgw2[27*576] | dyA[4*9*128*128] | dxA | maskA
// total = 36864 + 15552 + 3*589824 = 1,821,888 floats = 7.29 MB  (keep WELL under ws_size;
// Round-1's 24 MB footprint corrupted adjacent allocations -> post-timing divergence)

// ---------------- K1: pack weights ----------------
// wt[(kk*64 + c)*64 + o]   = weight[(o*64 + c)*9 + kk]
// pgw2[pp*576 + q*64 + c]  = pg_w[(pp*64 + c)*9 + q]
__global__ __launch_bounds__(256) void k_pack_w(const float* __restrict__ weight,
                                                const float* __restrict__ pg_w,
                                                float* __restrict__ wt,
                                                float* __restrict__ pgw2) {
    int idx = blockIdx.x * 256 + threadIdx.x;
    if (idx < 9 * 64 * 64) {
        int o = idx & 63; int rest = idx >> 6; int c = rest & 63; int kk = rest >> 6;
        wt[idx] = weight[(o * 64 + c) * 9 + kk];
    }
    int idx2 = idx - 9 * 64 * 64;
    if (idx2 >= 0 && idx2 < 27 * 576) {
        int c = idx2 & 63; int rest = idx2 >> 6; int q = rest % 9; int pp = rest / 9;
        pgw2[idx2] = pg_w[(pp * 64 + c) * 9 + q];
    }
}

// ---------------- K2: offset-generator conv (64 -> 27 ch, 3x3, pad 1) ----------------
// Grid: 1024 blocks (b, 16x16 tiles of 8x8 px), 256 threads.
// Stage 10x10x64 fp32 x-patch in LDS (zeros outside image = conv zero-pad).
// Thread = (pixel px=t&63, wave g=t>>6 handling params {g, g+4, ...}).
__global__ __launch_bounds__(256) void k_offset_conv(const float* __restrict__ x,
                                                     const float* __restrict__ pgw2,
                                                     const float* __restrict__ pg_b,
                                                     float* __restrict__ dyA,
                                                     float* __restrict__ dxA,
                                                     float* __restrict__ maskA) {
    __shared__ float xp[64 * 100];   // [c][y*10+x], rows h0-1..h0+8, cols w0-1..w0+8

    int bid = blockIdx.x;
    int b  = bid >> 8;
    int h0 = ((bid >> 4) & 15) * 8;
    int w0 = (bid & 15) * 8;
    int t = threadIdx.x;

    for (int idx = t; idx < 6400; idx += 256) {
        int c = idx / 100; int r = idx - c * 100;
        int yy = r / 10;   int xx = r - yy * 10;
        int gy = h0 - 1 + yy, gx = w0 - 1 + xx;
        float v = 0.f;
        if (((unsigned)gy < 128u) && ((unsigned)gx < 128u))
            v = x[(b * 64 + c) * 16384 + gy * 128 + gx];
        xp[idx] = v;
    }
    __syncthreads();

    int px = t & 63;
    int py = px >> 3, pxx = px & 7;
    int g = __builtin_amdgcn_readfirstlane(t >> 6);   // wave-uniform 0..3
    int hh = h0 + py, ww = w0 + pxx;

    float acc[7];
#pragma unroll
    for (int j = 0; j < 7; ++j) acc[j] = 0.f;

    for (int q = 0; q < 9; ++q) {
        int kh = q / 3, kw = q - 3 * kh;
        int aoff = (py + kh) * 10 + (pxx + kw);
        const float* bp = pgw2 + q * 64;
#pragma unroll 4
        for (int c = 0; c < 64; ++c) {
            float a = xp[c * 100 + aoff];
#pragma unroll
            for (int j = 0; j < 7; ++j) {
                int pp = g + 4 * j;
                if (pp < 27)   // wave-uniform
                    acc[j] += a * bp[pp * 576 + c];   // scalar-loadable (uniform addr)
            }
        }
    }
#pragma unroll
    for (int j = 0; j < 7; ++j) {
        int pp = g + 4 * j;
        if (pp < 27) {
            float v = acc[j] + pg_b[pp];
            if (pp < 18) {
                int n = pp >> 1;
                float* dst = (pp & 1) ? dxA : dyA;
                dst[(b * 9 + n) * 16384 + hh * 128 + ww] = v;
            } else {
                int n = pp - 18;
                maskA[(b * 9 + n) * 16384 + hh * 128 + ww] = 1.f / (1.f + expf(-v));
            }
        }
    }
}

// ---------------- K3: deformable sampling + output GEMM ----------------
// Grid: 1024 blocks (b, 8x8 px tile), 256 threads.
// Stage 16x16x64 bf16 x-patch (rows h0-4..h0+11) ONCE; per kk: bilinear-sample from
// patch (global fallback for rare large offsets) into a_s[c][px], stage weight slice
// b_s[c][o], then 4x4 register-tiled fp32 GEMM.
__global__ __launch_bounds__(256) void k_deform_main(const float* __restrict__ x,
                                                     const float* __restrict__ wt,
                                                     const float* __restrict__ bias,
                                                     const float* __restrict__ dyA,
                                                     const float* __restrict__ dxA,
                                                     const float* __restrict__ maskA,
                                                     float* __restrict__ out) {
    __shared__ __hip_bfloat16 xp[64 * 256];          // 32 KB  [c][yy*16+xx]
    __shared__ __align__(16) float a_s[64 * 68];     // 17.4 KB
    __shared__ __align__(16) float b_s[64 * 68];     // 17.4 KB

    int bid = blockIdx.x;
    int b  = bid >> 8;
    int h0 = ((bid >> 4) & 15) * 8;
    int w0 = (bid & 15) * 8;
    int t = threadIdx.x;
    int base_y = h0 - 4, base_x = w0 - 4;

    // stage x patch (bf16), zeros outside image
    for (int idx = t; idx < 16384; idx += 256) {
        int c = idx >> 8; int r = idx & 255;
        int yy = r >> 4;  int xx = r & 15;
        int gy = base_y + yy, gx = base_x + xx;
        float v = 0.f;
        if (((unsigned)gy < 128u) && ((unsigned)gx < 128u))
            v = x[(b * 64 + c) * 16384 + gy * 128 + gx];
        xp[idx] = __float2bfloat16(v);
    }

    int px_ = t & 63;            // sampling: this thread's pixel
    int g = t >> 6;              // sampling: channel group (16 ch)
    int spy = px_ >> 3, spx = px_ & 7;
    int hh = h0 + spy, ww = w0 + spx;

    int tx = t & 15;             // GEMM: pixel group (4 px)
    int ty = t >> 4;             // GEMM: output group (4 o)

    float acc[4][4];
#pragma unroll
    for (int i = 0; i < 4; ++i)
#pragma unroll
        for (int j = 0; j < 4; ++j) acc[i][j] = 0.f;

    __syncthreads();   // patch ready

    for (int kk = 0; kk < 9; ++kk) {
        // stage B slice: [c][o]
        for (int idx = t; idx < 4096; idx += 256)
            b_s[(idx >> 6) * 68 + (idx & 63)] = wt[kk * 4096 + idx];

        // bilinear params for this thread's pixel
        int ki = kk / 3, kj = kk - 3 * ki;
        int pbase = (b * 9 + kk) * 16384 + hh * 128 + ww;
        float dy = dyA[pbase], dxv = dxA[pbase], m = maskA[pbase];
        float ys = (float)(hh - 1 + ki) + dy;
        float xs = (float)(ww - 1 + kj) + dxv;
        float y0f = floorf(ys), x0f = floorf(xs);
        int y0 = (int)y0f, x0 = (int)x0f;
        float ly = ys - y0f, lx = xs - x0f;
        int y1 = y0 + 1, x1 = x0 + 1;
        float v0y = ((unsigned)y0 < 128u) ? 1.f : 0.f;
        float v1y = ((unsigned)y1 < 128u) ? 1.f : 0.f;
        float v0x = ((unsigned)x0 < 128u) ? 1.f : 0.f;
        float v1x = ((unsigned)x1 < 128u) ? 1.f : 0.f;
        float w00 = (1.f - ly) * (1.f - lx) * v0y * v0x;
        float w01 = (1.f - ly) * lx * v0y * v1x;
        float w10 = ly * (1.f - lx) * v1y * v0x;
        float w11 = ly * lx * v1y * v1x;
        int ly0 = y0 - base_y, lx0 = x0 - base_x;
        bool inp = ((unsigned)ly0 < 15u) && ((unsigned)lx0 < 15u);

        if (inp) {
            int aoff = ly0 * 16 + lx0;
            const __hip_bfloat16* pc = xp + g * 16 * 256 + aoff;
#pragma unroll 4
            for (int j = 0; j < 16; ++j) {
                int c = g * 16 + j;
                float s00 = __bfloat162float(pc[j * 256]);
                float s01 = __bfloat162float(pc[j * 256 + 1]);
                float s10 = __bfloat162float(pc[j * 256 + 16]);
                float s11 = __bfloat162float(pc[j * 256 + 17]);
                a_s[c * 68 + px_] = m * (w00 * s00 + w01 * s01 + w10 * s10 + w11 * s11);
            }
        } else {
            // rare: offset large enough to leave the patch — exact global path
            int y0c = min(max(y0, 0), 127), y1c = min(max(y1, 0), 127);
            int x0c = min(max(x0, 0), 127), x1c = min(max(x1, 0), 127);
            const float* xb = x + (b * 64 + g * 16) * 16384;
            for (int j = 0; j < 16; ++j) {
                int c = g * 16 + j;
                const float* xc = xb + j * 16384;
                float s00 = xc[y0c * 128 + x0c];
                float s01 = xc[y0c * 128 + x1c];
                float s10 = xc[y1c * 128 + x0c];
                float s11 = xc[y1c * 128 + x1c];
                a_s[c * 68 + px_] = m * (w00 * s00 + w01 * s01 + w10 * s10 + w11 * s11);
            }
        }
        __syncthreads();

        // GEMM over this kk's 64 channels
#pragma unroll 4
        for (int c = 0; c < 64; ++c) {
            float4 a4 = *(const float4*)&a_s[c * 68 + 4 * tx];
            float4 b4 = *(const float4*)&b_s[c * 68 + 4 * ty];
            acc[0][0] += b4.x * a4.x; acc[0][1] += b4.x * a4.y; acc[0][2] += b4.x * a4.z; acc[0][3] += b4.x * a4.w;
            acc[1][0] += b4.y * a4.x; acc[1][1] += b4.y * a4.y; acc[1][2] += b4.y * a4.z; acc[1][3] += b4.y * a4.w;
            acc[2][0] += b4.z * a4.x; acc[2][1] += b4.z * a4.y; acc[2][2] += b4.z * a4.z; acc[2][3] += b4.z * a4.w;
            acc[3][0] += b4.w * a4.x; acc[3][1] += b4.w * a4.y; acc[3][2] += b4.w * a4.z; acc[3][3] += b4.w * a4.w;
        }
        __syncthreads();
    }

    // epilogue: pixels {4tx..4tx+3} are contiguous in w within row tx>>1
    int epy = tx >> 1;
    int ehh = h0 + epy, ewwb = w0 + (tx & 1) * 4;
#pragma unroll
    for (int i = 0; i < 4; ++i) {
        int o = 4 * ty + i;
        float bo = bias[o];
        float4 v;
        v.x = acc[i][0] + bo; v.y = acc[i][1] + bo; v.z = acc[i][2] + bo; v.w = acc[i][3] + bo;
        *(float4*)&out[(b * 64 + o) * 16384 + ehh * 128 + ewwb] = v;
    }
}

extern "C" void kernel_launch(void* const* d_in, const int* in_sizes, int n_in,
                              void* d_out, int out_size, void* d_ws, size_t ws_size,
                              hipStream_t stream) {
    const float* x      = (const float*)d_in[0];
    const float* weight = (const float*)d_in[1];
    const float* bias   = (const float*)d_in[2];
    const float* pg_w   = (const float*)d_in[3];
    const float* pg_b   = (const float*)d_in[4];
    float* out = (float*)d_out;

    float* ws    = (float*)d_ws;
    float* wt    = ws;                      // 36,864
    float* pgw2  = wt + 36864;              // 15,552
    float* dyA   = pgw2 + 15552;            // 589,824
    float* dxA   = dyA + 589824;            // 589,824
    float* maskA = dxA + 589824;            // 589,824  -> total 7.29 MB

    k_pack_w<<<205, 256, 0, stream>>>(weight, pg_w, wt, pgw2);
    k_offset_conv<<<1024, 256, 0, stream>>>(x, pgw2, pg_b, dyA, dxA, maskA);
    k_deform_main<<<1024, 256, 0, stream>>>(x, wt, bias, dyA, dxA, maskA, out);
}

// Round 3
// 188.058 us; speedup vs baseline: 2.1199x; 2.1199x over previous
//
#include <hip/hip_runtime.h>
#include <math.h>

// B=4, C=64, H=W=128, O=64, K=3, pad=1, stride=1
// Both convs are GEMMs -> mfma_f32_16x16x32_bf16.
//   offset conv: M=65536 px, N=27->32, K=576
//   main conv  : M=65536 px, N=64,     K=576 (A = masked bilinear samples)
// ws (7.2 MB total; Round-1's 24 MB overflowed ws and corrupted neighbors):
//   dyA/dxA/maskA fp32 [4*9*128*128] each, then wtB/pgwB bf16 packed weights.

typedef __attribute__((ext_vector_type(8))) short short8;   // 8 bf16 = 4 VGPRs (A/B frag)
typedef __attribute__((ext_vector_type(4))) float f32x4;    // C/D frag

#define PW 72     // LDS row stride (elems): 144 B -> 4-bank rotation, <=2-way conflicts
#define BWP 584   // offset-weight row stride (576+8), 584%8==0 so pure b128 copies work

__device__ __forceinline__ float b2f(unsigned short h) {
    union { unsigned u; float f; } v; v.u = ((unsigned)h) << 16; return v.f;
}
__device__ __forceinline__ unsigned short f2b(float f) {   // RNE
    union { float f; unsigned u; } v; v.f = f;
    unsigned r = v.u + 0x7FFFu + ((v.u >> 16) & 1u);
    return (unsigned short)(r >> 16);
}

// ---------------- K1: pack weights to bf16, fragment-feed layouts ----------------
// wtB [kk][o][c]          (9*64*64)   = bf16(weight[(o*64+c)*9 + kk])
// pgwB[pp][q*64+c] pad584 (32*584)    = bf16(pg_w[(pp*64+c)*9 + q]), zeros for pp>=27 / k>=576
__global__ __launch_bounds__(256) void k_pack_w(const float* __restrict__ weight,
                                                const float* __restrict__ pg_w,
                                                unsigned short* __restrict__ wtB,
                                                unsigned short* __restrict__ pgwB) {
    int idx = blockIdx.x * 256 + threadIdx.x;
    if (idx < 36864) {
        int c = idx & 63, o = (idx >> 6) & 63, kk = idx >> 12;
        wtB[idx] = f2b(weight[(o * 64 + c) * 9 + kk]);
    }
    int i2 = idx - 36864;
    if (i2 >= 0 && i2 < 32 * BWP) {
        int pp = i2 / BWP, k = i2 - pp * BWP;
        float v = 0.f;
        if (pp < 27 && k < 576) {
            int q = k >> 6, c = k & 63;
            v = pg_w[(pp * 64 + c) * 9 + q];
        }
        pgwB[i2] = f2b(v);
    }
}

// ---------------- K2: offset-generator conv via MFMA ----------------
// 1024 blocks (b, 16x16 tiles of 8x8 px), 256 threads = 4 waves.
// Wave w owns m-tile (px 16w..16w+15); 2 n-tiles (params 0-15, 16-31); 18 k-blocks.
__global__ __launch_bounds__(256) void k_offset_mfma(const float* __restrict__ x,
                                                     const unsigned short* __restrict__ pgwB,
                                                     const float* __restrict__ pg_b,
                                                     float* __restrict__ dyA,
                                                     float* __restrict__ dxA,
                                                     float* __restrict__ maskA) {
    __shared__ unsigned short patch[100 * PW];   // 14.4 KB  [aoff(10x10)][c]
    __shared__ unsigned short bw[32 * BWP];      // 37.4 KB  [pp][k]

    int bid = blockIdx.x;
    int b  = bid >> 8;
    int h0 = ((bid >> 4) & 15) * 8;
    int w0 = (bid & 15) * 8;
    int t = threadIdx.x;

    // stage weights: contiguous b128 copy (2336 vec8 chunks)
    for (int i = t; i < 2336; i += 256)
        *(short8*)&bw[i * 8] = *(const short8*)&pgwB[i * 8];

    // stage patch: task (c, gy_i) reads a 10-px row, scatters bf16 into [aoff][c]
    for (int s = t; s < 640; s += 256) {
        int c = s / 10, gy_i = s - (s / 10) * 10;
        int gy = h0 - 1 + gy_i;
        bool vy = (unsigned)gy < 128u;
        const float* xr = x + (b * 64 + c) * 16384 + gy * 128;
        for (int gx_i = 0; gx_i < 10; ++gx_i) {
            int gx = w0 - 1 + gx_i;
            float v = (vy && ((unsigned)gx < 128u)) ? xr[gx] : 0.f;
            patch[(gy_i * 10 + gx_i) * PW + c] = f2b(v);
        }
    }
    __syncthreads();

    int l = t & 63, w = t >> 6;
    int quad = l >> 4;
    int mrow = w * 16 + (l & 15);
    int py = mrow >> 3, pxx = mrow & 7;
    f32x4 acc0 = {0.f, 0.f, 0.f, 0.f}, acc1 = {0.f, 0.f, 0.f, 0.f};
    int n0 = l & 15, n1 = (l & 15) + 16;

#pragma unroll
    for (int kb = 0; kb < 18; ++kb) {
        int q = kb >> 1;                 // compile-time (full unroll)
        int kh = q / 3, kw = q - 3 * q / 3 * 1;  // q%3
        kw = q - 3 * kh;
        int aoff = (py + kh) * 10 + (pxx + kw);
        int c0 = (kb & 1) * 32 + quad * 8;
        short8 af = *(const short8*)&patch[aoff * PW + c0];
        int k0 = kb * 32 + quad * 8;
        short8 b0 = *(const short8*)&bw[n0 * BWP + k0];
        short8 b1 = *(const short8*)&bw[n1 * BWP + k0];
        acc0 = __builtin_amdgcn_mfma_f32_16x16x32_bf16(af, b0, acc0, 0, 0, 0);
        acc1 = __builtin_amdgcn_mfma_f32_16x16x32_bf16(af, b1, acc1, 0, 0, 0);
    }

    // epilogue: D col = param (lane&15 [+16]), row = px = w*16 + quad*4 + i
#pragma unroll
    for (int tile = 0; tile < 2; ++tile) {
        int p = tile ? n1 : n0;
        f32x4 a = tile ? acc1 : acc0;
        if (p < 27) {
            float bo = pg_b[p];
#pragma unroll
            for (int i = 0; i < 4; ++i) {
                int px = w * 16 + quad * 4 + i;
                int hh = h0 + (px >> 3), ww = w0 + (px & 7);
                float v = a[i] + bo;
                if (p < 18) {
                    float* dst = (p & 1) ? dxA : dyA;
                    dst[(b * 9 + (p >> 1)) * 16384 + hh * 128 + ww] = v;
                } else {
                    maskA[(b * 9 + (p - 18)) * 16384 + hh * 128 + ww] = 1.f / (1.f + expf(-v));
                }
            }
        }
    }
}

// ---------------- K3: deformable sampling + main GEMM via MFMA ----------------
// 1024 blocks (b, 8x8 px), 256 threads = 4 waves.
// Per kk: vectorized bilinear sampling (8 ch / 4 b128 reads) -> a_s[px][c] bf16;
// weights b_s[o][c] bf16; per wave 2 kb x 4 n-tiles = 8 MFMAs.
__global__ __launch_bounds__(256) void k_deform_mfma(const float* __restrict__ x,
                                                     const unsigned short* __restrict__ wtB,
                                                     const float* __restrict__ bias,
                                                     const float* __restrict__ dyA,
                                                     const float* __restrict__ dxA,
                                                     const float* __restrict__ maskA,
                                                     float* __restrict__ out) {
    __shared__ unsigned short xp[256 * PW];   // 36.9 KB [yy*16+xx][c], rows h0-4..h0+11
    __shared__ unsigned short a_s[64 * PW];   // 9.2 KB  [px][c]
    __shared__ unsigned short b_s[64 * PW];   // 9.2 KB  [o][c]

    int bid = blockIdx.x;
    int b  = bid >> 8;
    int h0 = ((bid >> 4) & 15) * 8;
    int w0 = (bid & 15) * 8;
    int t = threadIdx.x;
    int base_y = h0 - 4, base_x = w0 - 4;

    // stage xp: task (c, yy) reads a 16-px row, scatters bf16
    for (int s = t; s < 1024; s += 256) {
        int c = s >> 4, yy = s & 15;
        int gy = base_y + yy;
        bool vy = (unsigned)gy < 128u;
        const float* xr = x + (b * 64 + c) * 16384 + gy * 128;
        for (int xx = 0; xx < 16; ++xx) {
            int gx = base_x + xx;
            float v = (vy && ((unsigned)gx < 128u)) ? xr[gx] : 0.f;
            xp[(yy * 16 + xx) * PW + c] = f2b(v);
        }
    }

    int l = t & 63, w = t >> 6;
    int quad = l >> 4;
    int px1 = t & 63;                 // sampling pixel
    int spy = px1 >> 3, spx = px1 & 7;
    int hh = h0 + spy, ww = w0 + spx;

    f32x4 acc[4];
#pragma unroll
    for (int nt = 0; nt < 4; ++nt) acc[nt] = (f32x4){0.f, 0.f, 0.f, 0.f};

    __syncthreads();

    for (int kk = 0; kk < 9; ++kk) {
        // stage b_s (b128 copies; contiguous global)
        for (int i = t; i < 512; i += 256) {
            int o = i >> 3, c0 = (i & 7) * 8;
            *(short8*)&b_s[o * PW + c0] = *(const short8*)&wtB[kk * 4096 + o * 64 + c0];
        }

        // bilinear params for this pixel
        int ki = kk / 3, kj = kk - 3 * (kk / 3);
        int pbase = (b * 9 + kk) * 16384 + hh * 128 + ww;
        float dy = dyA[pbase], dxv = dxA[pbase], m = maskA[pbase];
        float ys = (float)(hh - 1 + ki) + dy;
        float xs = (float)(ww - 1 + kj) + dxv;
        float y0f = floorf(ys), x0f = floorf(xs);
        int y0 = (int)y0f, x0 = (int)x0f;
        float ly = ys - y0f, lx = xs - x0f;
        int y1 = y0 + 1, x1 = x0 + 1;
        float v0y = ((unsigned)y0 < 128u) ? 1.f : 0.f;
        float v1y = ((unsigned)y1 < 128u) ? 1.f : 0.f;
        float v0x = ((unsigned)x0 < 128u) ? 1.f : 0.f;
        float v1x = ((unsigned)x1 < 128u) ? 1.f : 0.f;
        float w00 = (1.f - ly) * (1.f - lx) * v0y * v0x;
        float w01 = (1.f - ly) * lx * v0y * v1x;
        float w10 = ly * (1.f - lx) * v1y * v0x;
        float w11 = ly * lx * v1y * v1x;
        int ly0 = y0 - base_y, lx0 = x0 - base_x;
        bool inp = ((unsigned)ly0 < 15u) && ((unsigned)lx0 < 15u);

#pragma unroll
        for (int half = 0; half < 2; ++half) {
            int c0 = (w + half * 4) * 8;          // 8 channels
            short8 res;
            if (inp) {
                int aoff = ly0 * 16 + lx0;
                short8 r00 = *(const short8*)&xp[(aoff) * PW + c0];
                short8 r01 = *(const short8*)&xp[(aoff + 1) * PW + c0];
                short8 r10 = *(const short8*)&xp[(aoff + 16) * PW + c0];
                short8 r11 = *(const short8*)&xp[(aoff + 17) * PW + c0];
#pragma unroll
                for (int e = 0; e < 8; ++e) {
                    float v = w00 * b2f((unsigned short)r00[e]) + w01 * b2f((unsigned short)r01[e])
                            + w10 * b2f((unsigned short)r10[e]) + w11 * b2f((unsigned short)r11[e]);
                    res[e] = (short)f2b(m * v);
                }
            } else {  // rare large-offset path: exact global reads
                int y0c = min(max(y0, 0), 127), y1c = min(max(y1, 0), 127);
                int x0c = min(max(x0, 0), 127), x1c = min(max(x1, 0), 127);
#pragma unroll
                for (int e = 0; e < 8; ++e) {
                    const float* xc = x + (b * 64 + c0 + e) * 16384;
                    float v = w00 * xc[y0c * 128 + x0c] + w01 * xc[y0c * 128 + x1c]
                            + w10 * xc[y1c * 128 + x0c] + w11 * xc[y1c * 128 + x1c];
                    res[e] = (short)f2b(m * v);
                }
            }
            *(short8*)&a_s[px1 * PW + c0] = res;
        }
        __syncthreads();

        // MFMA: wave w = m-tile (px 16w..16w+15); 4 n-tiles; K=64 in 2 blocks
#pragma unroll
        for (int kb = 0; kb < 2; ++kb) {
            short8 af = *(const short8*)&a_s[(w * 16 + (l & 15)) * PW + kb * 32 + quad * 8];
#pragma unroll
            for (int nt = 0; nt < 4; ++nt) {
                short8 bf = *(const short8*)&b_s[(nt * 16 + (l & 15)) * PW + kb * 32 + quad * 8];
                acc[nt] = __builtin_amdgcn_mfma_f32_16x16x32_bf16(af, bf, acc[nt], 0, 0, 0);
            }
        }
        __syncthreads();
    }

    // epilogue: D col = o = nt*16 + (lane&15); row = px = w*16 + quad*4 + i
#pragma unroll
    for (int nt = 0; nt < 4; ++nt) {
        int o = nt * 16 + (l & 15);
        float bo = bias[o];
#pragma unroll
        for (int i = 0; i < 4; ++i) {
            int px = w * 16 + quad * 4 + i;
            int ehh = h0 + (px >> 3), eww = w0 + (px & 7);
            out[(b * 64 + o) * 16384 + ehh * 128 + eww] = acc[nt][i] + bo;
        }
    }
}

extern "C" void kernel_launch(void* const* d_in, const int* in_sizes, int n_in,
                              void* d_out, int out_size, void* d_ws, size_t ws_size,
                              hipStream_t stream) {
    const float* x      = (const float*)d_in[0];
    const float* weight = (const float*)d_in[1];
    const float* bias   = (const float*)d_in[2];
    const float* pg_w   = (const float*)d_in[3];
    const float* pg_b   = (const float*)d_in[4];
    float* out = (float*)d_out;

    float* ws    = (float*)d_ws;
    float* dyA   = ws;                       // 589,824 f
    float* dxA   = dyA + 589824;             // 589,824 f
    float* maskA = dxA + 589824;             // 589,824 f
    unsigned short* wtB  = (unsigned short*)(maskA + 589824);  // 36,864 bf16
    unsigned short* pgwB = wtB + 36864;                        // 32*584 bf16
    // total ~7.19 MB

    k_pack_w<<<218, 256, 0, stream>>>(weight, pg_w, wtB, pgwB);
    k_offset_mfma<<<1024, 256, 0, stream>>>(x, pgwB, pg_b, dyA, dxA, maskA);
    k_deform_mfma<<<1024, 256, 0, stream>>>(x, wtB, bias, dyA, dxA, maskA, out);
}

// Round 4
// 148.135 us; speedup vs baseline: 2.6912x; 1.2695x over previous
//
#include <hip/hip_runtime.h>
#include <math.h>

// B=4, C=64, H=W=128, O=64, K=3, pad=1, stride=1
// Round-4 structure: barrier-free inner loops.
//   - A-fragments sampled in-register (lane owns its quad's 8-channel slice)
//   - B-fragments loaded per-lane from global (weights L2-resident)
//   - LDS = swizzled x-patch only (stride 64, c ^= (pos&7)*8 -> conflict-free)
// ws: P[4*16384*32] fp32 pixel-major params | wtB bf16 | pgwB bf16  (~8.5 MB)

typedef __attribute__((ext_vector_type(8))) short short8;   // 8 bf16 (A/B frag)
typedef __attribute__((ext_vector_type(4))) float f32x4;    // C/D frag

#define BWP 584   // pgwB row stride (576+8)

__device__ __forceinline__ float b2f(unsigned short h) {
    union { unsigned u; float f; } v; v.u = ((unsigned)h) << 16; return v.f;
}
__device__ __forceinline__ unsigned short f2b(float f) {   // RNE
    union { float f; unsigned u; } v; v.f = f;
    unsigned r = v.u + 0x7FFFu + ((v.u >> 16) & 1u);
    return (unsigned short)(r >> 16);
}

// ---------------- K1: pack weights to bf16 ----------------
// wtB [kk][o][c] (9*64*64);  pgwB[pp][q*64+c] stride 584 (32 rows, zero-padded)
__global__ __launch_bounds__(256) void k_pack_w(const float* __restrict__ weight,
                                                const float* __restrict__ pg_w,
                                                unsigned short* __restrict__ wtB,
                                                unsigned short* __restrict__ pgwB) {
    int idx = blockIdx.x * 256 + threadIdx.x;
    if (idx < 36864) {
        int c = idx & 63, o = (idx >> 6) & 63, kk = idx >> 12;
        wtB[idx] = f2b(weight[(o * 64 + c) * 9 + kk]);
    }
    int i2 = idx - 36864;
    if (i2 >= 0 && i2 < 32 * BWP) {
        int pp = i2 / BWP, k = i2 - pp * BWP;
        float v = 0.f;
        if (pp < 27 && k < 576) {
            int q = k >> 6, c = k & 63;
            v = pg_w[(pp * 64 + c) * 9 + q];
        }
        pgwB[i2] = f2b(v);
    }
}

// ---------------- K2: offset-generator conv via MFMA ----------------
// 512 blocks (b x 16 x 8), tile = 8 rows x 16 cols. 256 threads = 4 waves.
// Wave w: m-tiles {w, w+4} (rows), n-tiles {0,1} (params 0-15,16-31).
// Patch: rows h0-1..h0+8 (10), cols w0-2..w0+17 (20), swizzled stride 64.
__global__ __launch_bounds__(256, 4) void k_offset_mfma(const float* __restrict__ x,
                                                        const unsigned short* __restrict__ pgwB,
                                                        const float* __restrict__ pg_b,
                                                        float* __restrict__ P) {
    __shared__ unsigned short patch[200 * 64];   // 25.6 KB

    int bid = blockIdx.x;
    int b  = bid >> 7;
    int h0 = ((bid >> 3) & 15) * 8;
    int w0 = (bid & 7) * 16;
    int t = threadIdx.x;

    // ---- stage patch: thread = (row yy<10, x-pair xx2<10), c-loop, float2 loads ----
    {
        int xx2 = t & 15, yy = t >> 4;
        if (xx2 < 10 && yy < 10) {
            int gy = h0 - 1 + yy;
            int gx0 = w0 - 2 + 2 * xx2;
            int pos0 = yy * 20 + 2 * xx2;
            int s0 = (pos0 & 7) * 8, s1 = ((pos0 + 1) & 7) * 8;
            bool vy = (unsigned)gy < 128u;
            bool v0 = vy && ((unsigned)gx0 < 128u);
            bool v1 = vy && ((unsigned)(gx0 + 1) < 128u);
            const float* xr = x + (size_t)b * 64 * 16384 + gy * 128 + gx0;
            if (v0 && v1) {
#pragma unroll 4
                for (int c = 0; c < 64; ++c) {
                    float2 a = *(const float2*)(xr + c * 16384);
                    patch[pos0 * 64 + (c ^ s0)] = f2b(a.x);
                    patch[(pos0 + 1) * 64 + (c ^ s1)] = f2b(a.y);
                }
            } else {
#pragma unroll 4
                for (int c = 0; c < 64; ++c) {
                    float a0 = v0 ? xr[c * 16384] : 0.f;
                    float a1 = v1 ? xr[c * 16384 + 1] : 0.f;
                    patch[pos0 * 64 + (c ^ s0)] = f2b(a0);
                    patch[(pos0 + 1) * 64 + (c ^ s1)] = f2b(a1);
                }
            }
        }
    }
    __syncthreads();

    int l = t & 63, w = t >> 6;
    int quad = l >> 4, ln = l & 15;

    f32x4 acc[2][2];
#pragma unroll
    for (int i = 0; i < 2; ++i)
#pragma unroll
        for (int j = 0; j < 2; ++j) acc[i][j] = (f32x4){0.f, 0.f, 0.f, 0.f};

#pragma unroll
    for (int kb = 0; kb < 18; ++kb) {
        int q = kb >> 1;
        int kh = q / 3, kw = q - 3 * (q / 3);
        int k0 = kb * 32 + quad * 8;
        short8 b0 = *(const short8*)&pgwB[ln * BWP + k0];          // global (L2-hot)
        short8 b1 = *(const short8*)&pgwB[(16 + ln) * BWP + k0];
        int c0 = (kb & 1) * 32 + quad * 8;
#pragma unroll
        for (int mt2 = 0; mt2 < 2; ++mt2) {
            int mt = w + mt2 * 4;
            int aoff = (mt + kh) * 20 + (ln + kw + 1);
            short8 af = *(const short8*)&patch[aoff * 64 + (c0 ^ ((aoff & 7) * 8))];
            acc[mt2][0] = __builtin_amdgcn_mfma_f32_16x16x32_bf16(af, b0, acc[mt2][0], 0, 0, 0);
            acc[mt2][1] = __builtin_amdgcn_mfma_f32_16x16x32_bf16(af, b1, acc[mt2][1], 0, 0, 0);
        }
    }

    // epilogue -> P[(b*16384 + pix)*32 + p]; p<18 raw (dy/dx interleaved), 18..26 sigmoid
#pragma unroll
    for (int tile = 0; tile < 2; ++tile) {
        int p = tile * 16 + ln;
        if (p < 27) {
            float bo = pg_b[p];
#pragma unroll
            for (int mt2 = 0; mt2 < 2; ++mt2) {
                int mt = w + mt2 * 4;
#pragma unroll
                for (int i = 0; i < 4; ++i) {
                    int pix = (h0 + mt) * 128 + (w0 + quad * 4 + i);
                    float v = acc[mt2][tile][i] + bo;
                    if (p >= 18) v = 1.f / (1.f + expf(-v));
                    P[((size_t)b * 16384 + pix) * 32 + p] = v;
                }
            }
        }
    }
}

// ---------------- K3: deformable sampling + main GEMM via MFMA ----------------
// 1024 blocks (b x 16 x 16), tile = 8x8 px. 256 threads = 4 waves.
// Wave w: m-tile w (16 px), n-tiles 0..3. Barrier-free kk loop:
//   A sampled in-register from swizzled patch; B per-lane from global wtB.
// Patch: rows h0-2..h0+10 (13), cols w0-2..w0+11 (14, stride 14), covers |d|<1 (4 sigma).
__global__ __launch_bounds__(256, 4) void k_deform_mfma(const float* __restrict__ x,
                                                        const unsigned short* __restrict__ wtB,
                                                        const float* __restrict__ bias,
                                                        const float* __restrict__ P,
                                                        float* __restrict__ out) {
    __shared__ unsigned short patch[182 * 64];   // 23.3 KB

    int bid = blockIdx.x;
    int b  = bid >> 8;
    int h0 = ((bid >> 4) & 15) * 8;
    int w0 = (bid & 15) * 8;
    int t = threadIdx.x;
    int base_y = h0 - 2, base_x = w0 - 2;

    // ---- stage patch: thread = (row yy<13, x-pair xx2<7), c-loop, float2 loads ----
    {
        int xx2 = t & 7, yy = t >> 3;
        if (xx2 < 7 && yy < 13) {
            int gy = base_y + yy;
            int gx0 = base_x + 2 * xx2;
            int pos0 = yy * 14 + 2 * xx2;
            int s0 = (pos0 & 7) * 8, s1 = ((pos0 + 1) & 7) * 8;
            bool vy = (unsigned)gy < 128u;
            bool v0 = vy && ((unsigned)gx0 < 128u);
            bool v1 = vy && ((unsigned)(gx0 + 1) < 128u);
            const float* xr = x + (size_t)b * 64 * 16384 + gy * 128 + gx0;
            if (v0 && v1) {
#pragma unroll 4
                for (int c = 0; c < 64; ++c) {
                    float2 a = *(const float2*)(xr + c * 16384);
                    patch[pos0 * 64 + (c ^ s0)] = f2b(a.x);
                    patch[(pos0 + 1) * 64 + (c ^ s1)] = f2b(a.y);
                }
            } else {
#pragma unroll 4
                for (int c = 0; c < 64; ++c) {
                    float a0 = v0 ? xr[c * 16384] : 0.f;
                    float a1 = v1 ? xr[c * 16384 + 1] : 0.f;
                    patch[pos0 * 64 + (c ^ s0)] = f2b(a0);
                    patch[(pos0 + 1) * 64 + (c ^ s1)] = f2b(a1);
                }
            }
        }
    }
    __syncthreads();

    int l = t & 63, w = t >> 6;
    int quad = l >> 4, ln = l & 15;
    int px = w * 16 + ln;
    int hh = h0 + (px >> 3), ww = w0 + (px & 7);
    size_t pixbase = ((size_t)b * 16384 + hh * 128 + ww) * 32;

    f32x4 acc[4];
#pragma unroll
    for (int nt = 0; nt < 4; ++nt) acc[nt] = (f32x4){0.f, 0.f, 0.f, 0.f};

    for (int kk = 0; kk < 9; ++kk) {
        // B-fragments: per-lane global loads (issue early)
        const unsigned short* wk = wtB + kk * 4096;
        short8 bfr[2][4];
#pragma unroll
        for (int kb = 0; kb < 2; ++kb)
#pragma unroll
            for (int nt = 0; nt < 4; ++nt)
                bfr[kb][nt] = *(const short8*)&wk[(nt * 16 + ln) * 64 + kb * 32 + quad * 8];

        // bilinear params
        int ki = kk / 3, kj = kk - 3 * (kk / 3);
        float2 d2 = *(const float2*)&P[pixbase + 2 * kk];
        float m = P[pixbase + 18 + kk];
        float ys = (float)(hh - 1 + ki) + d2.x;
        float xs = (float)(ww - 1 + kj) + d2.y;
        float y0f = floorf(ys), x0f = floorf(xs);
        int y0 = (int)y0f, x0 = (int)x0f;
        float ly = ys - y0f, lx = xs - x0f;
        float v0y = ((unsigned)y0 < 128u) ? 1.f : 0.f;
        float v1y = ((unsigned)(y0 + 1) < 128u) ? 1.f : 0.f;
        float v0x = ((unsigned)x0 < 128u) ? 1.f : 0.f;
        float v1x = ((unsigned)(x0 + 1) < 128u) ? 1.f : 0.f;
        float w00 = (1.f - ly) * (1.f - lx) * v0y * v0x * m;
        float w01 = (1.f - ly) * lx * v0y * v1x * m;
        float w10 = ly * (1.f - lx) * v1y * v0x * m;
        float w11 = ly * lx * v1y * v1x * m;
        int ly0 = y0 - base_y, lx0 = x0 - base_x;
        bool inp = ((unsigned)ly0 < 12u) && ((unsigned)lx0 < 12u);

        short8 af[2];
        if (inp) {
            int pos = ly0 * 14 + lx0;
#pragma unroll
            for (int kb = 0; kb < 2; ++kb) {
                int c0 = kb * 32 + quad * 8;
                short8 r00 = *(const short8*)&patch[pos * 64 + (c0 ^ ((pos & 7) * 8))];
                short8 r01 = *(const short8*)&patch[(pos + 1) * 64 + (c0 ^ (((pos + 1) & 7) * 8))];
                short8 r10 = *(const short8*)&patch[(pos + 14) * 64 + (c0 ^ (((pos + 14) & 7) * 8))];
                short8 r11 = *(const short8*)&patch[(pos + 15) * 64 + (c0 ^ (((pos + 15) & 7) * 8))];
#pragma unroll
                for (int e = 0; e < 8; ++e) {
                    float v = w00 * b2f((unsigned short)r00[e]) + w01 * b2f((unsigned short)r01[e])
                            + w10 * b2f((unsigned short)r10[e]) + w11 * b2f((unsigned short)r11[e]);
                    af[kb][e] = (short)f2b(v);
                }
            }
        } else {   // rare (|offset| >= 1): exact global path, clamped corners
            int y0c = min(max(y0, 0), 127), y1c = min(max(y0 + 1, 0), 127);
            int x0c = min(max(x0, 0), 127), x1c = min(max(x0 + 1, 0), 127);
#pragma unroll
            for (int kb = 0; kb < 2; ++kb) {
                int c0 = kb * 32 + quad * 8;
                for (int e = 0; e < 8; ++e) {
                    const float* xc = x + ((size_t)b * 64 + c0 + e) * 16384;
                    float v = w00 * xc[y0c * 128 + x0c] + w01 * xc[y0c * 128 + x1c]
                            + w10 * xc[y1c * 128 + x0c] + w11 * xc[y1c * 128 + x1c];
                    af[kb][e] = (short)f2b(v);
                }
            }
        }

#pragma unroll
        for (int kb = 0; kb < 2; ++kb)
#pragma unroll
            for (int nt = 0; nt < 4; ++nt)
                acc[nt] = __builtin_amdgcn_mfma_f32_16x16x32_bf16(af[kb], bfr[kb][nt], acc[nt], 0, 0, 0);
    }

    // epilogue: lane's 4 rows per nt are 4 consecutive ww -> float4 store
    int px0 = w * 16 + quad * 4;
    int ehh = h0 + (px0 >> 3), eww = w0 + (px0 & 7);
#pragma unroll
    for (int nt = 0; nt < 4; ++nt) {
        int o = nt * 16 + ln;
        float bo = bias[o];
        float4 v;
        v.x = acc[nt][0] + bo; v.y = acc[nt][1] + bo;
        v.z = acc[nt][2] + bo; v.w = acc[nt][3] + bo;
        *(float4*)&out[((size_t)b * 64 + o) * 16384 + ehh * 128 + eww] = v;
    }
}

extern "C" void kernel_launch(void* const* d_in, const int* in_sizes, int n_in,
                              void* d_out, int out_size, void* d_ws, size_t ws_size,
                              hipStream_t stream) {
    const float* x      = (const float*)d_in[0];
    const float* weight = (const float*)d_in[1];
    const float* bias   = (const float*)d_in[2];
    const float* pg_w   = (const float*)d_in[3];
    const float* pg_b   = (const float*)d_in[4];
    float* out = (float*)d_out;

    float* P = (float*)d_ws;                                   // 4*16384*32 f = 8.39 MB
    unsigned short* wtB  = (unsigned short*)(P + 4 * 16384 * 32);  // 36,864 bf16
    unsigned short* pgwB = wtB + 36864;                            // 32*584 bf16
    // total ~8.5 MB (Round-2/3 proved ~7.3 MB safe; stay small)

    k_pack_w<<<218, 256, 0, stream>>>(weight, pg_w, wtB, pgwB);
    k_offset_mfma<<<512, 256, 0, stream>>>(x, pgwB, pg_b, P);
    k_deform_mfma<<<1024, 256, 0, stream>>>(x, wtB, bias, P, out);
}

// Round 5
// 128.129 us; speedup vs baseline: 3.1114x; 1.1561x over previous
//
#include <hip/hip_runtime.h>
#include <math.h>

// B=4, C=64, H=W=128, O=64, K=3, pad=1, stride=1
// Round-5: single fused kernel per tile (8x8 px), 1024 blocks, 4 waves.
//   phase 0: stage 13x14x64 bf16 x-patch (XOR-swizzled, stride 64)
//   phase 1: offset conv via MFMA (M=64 px, N=32 params, K=576), params -> LDS P_s
//   phase 2: in-register bilinear sampling + main GEMM via MFMA (M=64,N=64,K=576)
// No P round-trip through HBM; B operands stay global (L2-hot).
// ws: wtB bf16 + pgwB bf16 only (~111 KB).

typedef __attribute__((ext_vector_type(8))) short short8;   // 8 bf16 (A/B frag)
typedef __attribute__((ext_vector_type(4))) float f32x4;    // C/D frag

#define BWP 584   // pgwB row stride (576+8)

__device__ __forceinline__ float b2f(unsigned short h) {
    union { unsigned u; float f; } v; v.u = ((unsigned)h) << 16; return v.f;
}
__device__ __forceinline__ unsigned short f2b(float f) {   // RNE
    union { float f; unsigned u; } v; v.f = f;
    unsigned r = v.u + 0x7FFFu + ((v.u >> 16) & 1u);
    return (unsigned short)(r >> 16);
}

// ---------------- K1: pack weights to bf16 ----------------
// wtB [kk][o][c] (9*64*64);  pgwB[pp][q*64+c] stride 584 (32 rows, zero-padded)
__global__ __launch_bounds__(256) void k_pack_w(const float* __restrict__ weight,
                                                const float* __restrict__ pg_w,
                                                unsigned short* __restrict__ wtB,
                                                unsigned short* __restrict__ pgwB) {
    int idx = blockIdx.x * 256 + threadIdx.x;
    if (idx < 36864) {
        int c = idx & 63, o = (idx >> 6) & 63, kk = idx >> 12;
        wtB[idx] = f2b(weight[(o * 64 + c) * 9 + kk]);
    }
    int i2 = idx - 36864;
    if (i2 >= 0 && i2 < 32 * BWP) {
        int pp = i2 / BWP, k = i2 - pp * BWP;
        float v = 0.f;
        if (pp < 27 && k < 576) {
            int q = k >> 6, c = k & 63;
            v = pg_w[(pp * 64 + c) * 9 + q];
        }
        pgwB[i2] = f2b(v);
    }
}

// ---------------- K2: fused offset-conv + deformable conv ----------------
// 1024 blocks (b x 16 x 16), tile = 8x8 px. 256 threads = 4 waves.
// Patch rows h0-2..h0+10 (13), cols w0-2..w0+11 (14); covers conv taps AND |d|<1 sampling.
__global__ __launch_bounds__(256, 4) void k_fused(const float* __restrict__ x,
                                                  const unsigned short* __restrict__ pgwB,
                                                  const float* __restrict__ pg_b,
                                                  const unsigned short* __restrict__ wtB,
                                                  const float* __restrict__ bias,
                                                  float* __restrict__ out) {
    __shared__ unsigned short patch[182 * 64];   // 23.3 KB [pos=yy*14+xx][c^swz]
    __shared__ float P_s[27 * 65];               // 7.0 KB  [param][px], stride 65

    int bid = blockIdx.x;
    int b  = bid >> 8;
    int h0 = ((bid >> 4) & 15) * 8;
    int w0 = (bid & 15) * 8;
    int t = threadIdx.x;
    int base_y = h0 - 2, base_x = w0 - 2;

    // ---- phase 0: stage patch (thread = (row yy<13, x-pair xx2<7), c-loop, float2) ----
    {
        int xx2 = t & 7, yy = t >> 3;
        if (xx2 < 7 && yy < 13) {
            int gy = base_y + yy;
            int gx0 = base_x + 2 * xx2;
            int pos0 = yy * 14 + 2 * xx2;
            int s0 = (pos0 & 7) * 8, s1 = ((pos0 + 1) & 7) * 8;
            bool vy = (unsigned)gy < 128u;
            bool v0 = vy && ((unsigned)gx0 < 128u);
            bool v1 = vy && ((unsigned)(gx0 + 1) < 128u);
            const float* xr = x + (size_t)b * 64 * 16384 + gy * 128 + gx0;
            if (v0 && v1) {
#pragma unroll 4
                for (int c = 0; c < 64; ++c) {
                    float2 a = *(const float2*)(xr + c * 16384);
                    patch[pos0 * 64 + (c ^ s0)] = f2b(a.x);
                    patch[(pos0 + 1) * 64 + (c ^ s1)] = f2b(a.y);
                }
            } else {
#pragma unroll 4
                for (int c = 0; c < 64; ++c) {
                    float a0 = v0 ? xr[c * 16384] : 0.f;
                    float a1 = v1 ? xr[c * 16384 + 1] : 0.f;
                    patch[pos0 * 64 + (c ^ s0)] = f2b(a0);
                    patch[(pos0 + 1) * 64 + (c ^ s1)] = f2b(a1);
                }
            }
        }
    }
    __syncthreads();

    int l = t & 63, w = t >> 6;
    int quad = l >> 4, ln = l & 15;

    // ---- phase 1: offset conv MFMA. Wave w -> m-tile w (16 px), n-tiles {0,1}. ----
    {
        int py = (w * 16 + ln) >> 3, pxx = (w * 16 + ln) & 7;   // m = ln within wave tile
        f32x4 oacc0 = {0.f, 0.f, 0.f, 0.f}, oacc1 = {0.f, 0.f, 0.f, 0.f};
#pragma unroll
        for (int kb = 0; kb < 18; ++kb) {
            int q = kb >> 1;
            int kh = q / 3, kw = q - 3 * (q / 3);
            int k0 = kb * 32 + quad * 8;
            short8 b0 = *(const short8*)&pgwB[ln * BWP + k0];          // L2-hot
            short8 b1 = *(const short8*)&pgwB[(16 + ln) * BWP + k0];
            int aoff = (py + kh + 1) * 14 + (pxx + kw + 1);
            int c0 = (kb & 1) * 32 + quad * 8;
            short8 af = *(const short8*)&patch[aoff * 64 + (c0 ^ ((aoff & 7) * 8))];
            oacc0 = __builtin_amdgcn_mfma_f32_16x16x32_bf16(af, b0, oacc0, 0, 0, 0);
            oacc1 = __builtin_amdgcn_mfma_f32_16x16x32_bf16(af, b1, oacc1, 0, 0, 0);
        }
        // D: col = param = tile*16 + ln, row(local) = quad*4 + i, px = w*16 + row
#pragma unroll
        for (int tile = 0; tile < 2; ++tile) {
            int p = tile * 16 + ln;
            f32x4 a = tile ? oacc1 : oacc0;
            if (p < 27) {
                float bo = pg_b[p];
#pragma unroll
                for (int i = 0; i < 4; ++i) {
                    int px = w * 16 + quad * 4 + i;
                    float v = a[i] + bo;
                    if (p >= 18) v = 1.f / (1.f + expf(-v));
                    P_s[p * 65 + px] = v;
                }
            }
        }
    }
    __syncthreads();

    // ---- phase 2: sampling + main GEMM. Wave w -> m-tile w; sampling pixel = w*16+ln ----
    int px = w * 16 + ln;
    int hh = h0 + (px >> 3), ww = w0 + (px & 7);

    f32x4 acc[4];
#pragma unroll
    for (int nt = 0; nt < 4; ++nt) acc[nt] = (f32x4){0.f, 0.f, 0.f, 0.f};

    for (int kk = 0; kk < 9; ++kk) {
        // B-fragments: per-lane global loads (L2-hot), issue early
        const unsigned short* wk = wtB + kk * 4096;
        short8 bfr[2][4];
#pragma unroll
        for (int kb = 0; kb < 2; ++kb)
#pragma unroll
            for (int nt = 0; nt < 4; ++nt)
                bfr[kb][nt] = *(const short8*)&wk[(nt * 16 + ln) * 64 + kb * 32 + quad * 8];

        // bilinear params (LDS; quads broadcast, px consecutive -> conflict-free)
        int ki = kk / 3, kj = kk - 3 * (kk / 3);
        float dyv = P_s[(2 * kk) * 65 + px];
        float dxv = P_s[(2 * kk + 1) * 65 + px];
        float m   = P_s[(18 + kk) * 65 + px];
        float ys = (float)(hh - 1 + ki) + dyv;
        float xs = (float)(ww - 1 + kj) + dxv;
        float y0f = floorf(ys), x0f = floorf(xs);
        int y0 = (int)y0f, x0 = (int)x0f;
        float ly = ys - y0f, lx = xs - x0f;
        float v0y = ((unsigned)y0 < 128u) ? 1.f : 0.f;
        float v1y = ((unsigned)(y0 + 1) < 128u) ? 1.f : 0.f;
        float v0x = ((unsigned)x0 < 128u) ? 1.f : 0.f;
        float v1x = ((unsigned)(x0 + 1) < 128u) ? 1.f : 0.f;
        float w00 = (1.f - ly) * (1.f - lx) * v0y * v0x * m;
        float w01 = (1.f - ly) * lx * v0y * v1x * m;
        float w10 = ly * (1.f - lx) * v1y * v0x * m;
        float w11 = ly * lx * v1y * v1x * m;
        int ly0 = y0 - base_y, lx0 = x0 - base_x;
        bool inp = ((unsigned)ly0 < 12u) && ((unsigned)lx0 < 12u);

        short8 af[2];
        if (inp) {
            int pos = ly0 * 14 + lx0;
#pragma unroll
            for (int kb = 0; kb < 2; ++kb) {
                int c0 = kb * 32 + quad * 8;
                short8 r00 = *(const short8*)&patch[pos * 64 + (c0 ^ ((pos & 7) * 8))];
                short8 r01 = *(const short8*)&patch[(pos + 1) * 64 + (c0 ^ (((pos + 1) & 7) * 8))];
                short8 r10 = *(const short8*)&patch[(pos + 14) * 64 + (c0 ^ (((pos + 14) & 7) * 8))];
                short8 r11 = *(const short8*)&patch[(pos + 15) * 64 + (c0 ^ (((pos + 15) & 7) * 8))];
#pragma unroll
                for (int e = 0; e < 8; ++e) {
                    float v = w00 * b2f((unsigned short)r00[e]) + w01 * b2f((unsigned short)r01[e])
                            + w10 * b2f((unsigned short)r10[e]) + w11 * b2f((unsigned short)r11[e]);
                    af[kb][e] = (short)f2b(v);
                }
            }
        } else {   // rare (|offset| >= 1): exact global path, clamped corners
            int y0c = min(max(y0, 0), 127), y1c = min(max(y0 + 1, 0), 127);
            int x0c = min(max(x0, 0), 127), x1c = min(max(x0 + 1, 0), 127);
#pragma unroll
            for (int kb = 0; kb < 2; ++kb) {
                int c0 = kb * 32 + quad * 8;
                for (int e = 0; e < 8; ++e) {
                    const float* xc = x + ((size_t)b * 64 + c0 + e) * 16384;
                    float v = w00 * xc[y0c * 128 + x0c] + w01 * xc[y0c * 128 + x1c]
                            + w10 * xc[y1c * 128 + x0c] + w11 * xc[y1c * 128 + x1c];
                    af[kb][e] = (short)f2b(v);
                }
            }
        }

#pragma unroll
        for (int kb = 0; kb < 2; ++kb)
#pragma unroll
            for (int nt = 0; nt < 4; ++nt)
                acc[nt] = __builtin_amdgcn_mfma_f32_16x16x32_bf16(af[kb], bfr[kb][nt], acc[nt], 0, 0, 0);
    }

    // ---- epilogue: lane's 4 rows per nt are 4 consecutive ww -> float4 store ----
    int px0 = w * 16 + quad * 4;
    int ehh = h0 + (px0 >> 3), eww = w0 + (px0 & 7);
#pragma unroll
    for (int nt = 0; nt < 4; ++nt) {
        int o = nt * 16 + ln;
        float bo = bias[o];
        float4 v;
        v.x = acc[nt][0] + bo; v.y = acc[nt][1] + bo;
        v.z = acc[nt][2] + bo; v.w = acc[nt][3] + bo;
        *(float4*)&out[((size_t)b * 64 + o) * 16384 + ehh * 128 + eww] = v;
    }
}

extern "C" void kernel_launch(void* const* d_in, const int* in_sizes, int n_in,
                              void* d_out, int out_size, void* d_ws, size_t ws_size,
                              hipStream_t stream) {
    const float* x      = (const float*)d_in[0];
    const float* weight = (const float*)d_in[1];
    const float* bias   = (const float*)d_in[2];
    const float* pg_w   = (const float*)d_in[3];
    const float* pg_b   = (const float*)d_in[4];
    float* out = (float*)d_out;

    unsigned short* wtB  = (unsigned short*)d_ws;   // 36,864 bf16
    unsigned short* pgwB = wtB + 36864;             // 32*584 bf16   (~111 KB total)

    k_pack_w<<<218, 256, 0, stream>>>(weight, pg_w, wtB, pgwB);
    k_fused<<<1024, 256, 0, stream>>>(x, pgwB, pg_b, wtB, bias, out);
}